// Round 16
// baseline (115.689 us; speedup 1.0000x reference)
//
#include <hip/hip_runtime.h>
#include <hip/hip_bf16.h>

#define NBH  32          // B*H
#define SEQ  2048
#define DIM  64
#define PSTR 2056        // ushorts per P row (pad +8 -> 2-way A-frag reads, free)

typedef __attribute__((ext_vector_type(4))) float f32x4;
typedef __attribute__((ext_vector_type(8))) short bf16x8;

__device__ __forceinline__ unsigned short bfbits(float f) {
    unsigned u = __builtin_bit_cast(unsigned, f);
    u += 0x7FFFu + ((u >> 16) & 1u);          // RTNE
    return (unsigned short)(u >> 16);
}
__device__ __forceinline__ unsigned pk(float a, float b) {
    return (unsigned)bfbits(a) | ((unsigned)bfbits(b) << 16);
}

// ---------------------------------------------------------------------------
// V prep (unchanged layout): ws[bh][tau][ks][dt][lane][j] = bf16 of
//   V[bh][tau*64 + ks*32 + (lane>>4)*8 + j][dt*16 + (lane&15)]
// => B-frag for global k-slice K32 (0..63), dt at ushort offset K32*2048+dt*512.
// ---------------------------------------------------------------------------
__global__ __launch_bounds__(256)
void vprep_kernel(const float* __restrict__ v, unsigned short* __restrict__ wsv)
{
    const int blk = blockIdx.x;            // bh*32 + tau
    const int bh  = blk >> 5, tau = blk & 31;
    const float* vp = v + ((size_t)bh * SEQ + tau * 64) * DIM;
    unsigned short* op = wsv + (size_t)blk * 4096;

    for (int fl = threadIdx.x; fl < 512; fl += 256) {
        const int ks = fl >> 8, dt = (fl >> 6) & 3, lane = fl & 63;
        const int g = lane >> 4, c = lane & 15;
        const float* sp = vp + (ks * 32 + g * 8) * DIM + dt * 16 + c;
        bf16x8 frag;
#pragma unroll
        for (int j = 0; j < 8; ++j)
            frag[j] = (short)bfbits(sp[j * DIM]);
        *reinterpret_cast<bf16x8*>(op + fl * 8) = frag;
    }
}

// ---------------------------------------------------------------------------
// Main kernel (r15 + SINGLE-FRONT pack): persistent 1 block/CU, 512 threads.
// Pack loop: per iteration the WHOLE BLOCK consumes one contiguous 8KB row
// (thread T <- floats [T*4,T*4+4)); ring of 8 rows in registers; row r+8
// issued as row r is consumed -> ONE strictly sequential 2MB stream per CU
// (probe-B geometry). exp+pack -> P-LDS (transpose); V register-resident
// (wave=(dt,ksub)); ones-column MFMA denominator; k-half reduce via LDS.
// Two lgkm-only barriers per tile, zero vmcnt drains.
// ---------------------------------------------------------------------------
__global__ __launch_bounds__(512, 2)
void softmaxv_kernel(const float* __restrict__ scores,
                     const unsigned short* __restrict__ vfrags,
                     float* __restrict__ out)
{
    __shared__ unsigned short P[16 * PSTR];   // 65,792 B
    __shared__ float red[4][64][8];           // 8,192 B

    const int tid  = threadIdx.x;
    const int w    = tid >> 6;        // 0..7
    const int lane = tid & 63;
    const int dt   = w & 3;           // output col slice
    const int ksub = w >> 2;          // k half (0: k<1024, 1: k>=1024)
    const int g    = lane >> 4;       // 0..3
    const int c    = lane & 15;       // 0..15

    const int bid = blockIdx.x;
    const int bh  = bid & 31;         // same-bh blocks share an XCD (bid%8)
    const int s   = bid >> 5;         // q-range [s*256, s*256+256)

    const float* sblk = scores + ((size_t)bh * SEQ + s * 256) * SEQ;
    const unsigned short* vb = vfrags + (size_t)bh * 32 * 4096 + lane * 8;
    float* const oblk = out + ((size_t)bh * SEQ + s * 256) * DIM;

    bf16x8 ones;
#pragma unroll
    for (int j = 0; j < 8; ++j) ones[j] = (short)0x3F80;   // bf16 1.0

    // ---- V fragments register-resident: 32 slices for this (ksub, dt) ----
    bf16x8 vreg[32];
#pragma unroll
    for (int kk = 0; kk < 32; ++kk)
        vreg[kk] = *reinterpret_cast<const bf16x8*>(
            vb + (size_t)(ksub * 32 + kk) * 2048 + dt * 512);

    f32x4 st[8];                      // 8-row ring; slot = row & 7 (static idx)

#define LOADR(R, slot)                                                         \
    st[slot] = *reinterpret_cast<const f32x4*>(                                \
        sblk + (size_t)(R) * SEQ + tid * 4);

#define LDS_BAR asm volatile("s_waitcnt lgkmcnt(0)\n\ts_barrier" ::: "memory");

    // prime rows 0..7 (one sequential front)
    LOADR(0, 0) LOADR(1, 1) LOADR(2, 2) LOADR(3, 3)
    LOADR(4, 4) LOADR(5, 5) LOADR(6, 6) LOADR(7, 7)

    for (int t = 0; t < 16; ++t) {
        // ---- pack: block-wide row fronts; consume row R, reissue row R+8 ----
#pragma unroll
        for (int r = 0; r < 16; ++r) {
            const f32x4 sv = st[r & 7];            // consume first
            const int R = t * 16 + r;
            if (R + 8 < 256) { LOADR(R + 8, r & 7) }   // then refill slot
            const float e0 = __expf(sv[0]), e1 = __expf(sv[1]);
            const float e2 = __expf(sv[2]), e3 = __expf(sv[3]);
            *reinterpret_cast<uint2*>(&P[r * PSTR + tid * 4]) =
                make_uint2(pk(e0, e1), pk(e2, e3));
        }

        LDS_BAR   // P visible; S loads stay in flight (lgkm-only)

        // ---- MFMA: 32 k-slices for this (ksub, dt) ----
        f32x4 acc  = (f32x4)0.0f;
        f32x4 accl = (f32x4)0.0f;
#pragma unroll
        for (int kk = 0; kk < 32; ++kk) {
            const int K = ksub * 32 + kk;
            const bf16x8 a = *reinterpret_cast<const bf16x8*>(
                &P[c * PSTR + K * 32 + g * 8]);
            acc  = __builtin_amdgcn_mfma_f32_16x16x32_bf16(a, vreg[kk], acc,  0, 0, 0);
            accl = __builtin_amdgcn_mfma_f32_16x16x32_bf16(a, ones,     accl, 0, 0, 0);
        }

        if (ksub == 1) {
            *reinterpret_cast<f32x4*>(&red[dt][lane][0]) = acc;
            *reinterpret_cast<f32x4*>(&red[dt][lane][4]) = accl;
        }

        LDS_BAR   // red visible AND all P reads done before next pack

        if (ksub == 0) {
            const f32x4 a2 = *reinterpret_cast<const f32x4*>(&red[dt][lane][0]);
            const f32x4 l2 = *reinterpret_cast<const f32x4*>(&red[dt][lane][4]);
            const f32x4 at = acc + a2;
            const f32x4 lt = accl + l2;
            float* op = oblk + (size_t)(t * 16) * DIM + dt * 16 + c;
#pragma unroll
            for (int r = 0; r < 4; ++r)
                op[(size_t)(g * 4 + r) * DIM] = at[r] * (1.0f / lt[r]);
        }
    }
#undef LOADR
#undef LDS_BAR
}

extern "C" void kernel_launch(void* const* d_in, const int* in_sizes, int n_in,
                              void* d_out, int out_size, void* d_ws, size_t ws_size,
                              hipStream_t stream)
{
    const float* scores = (const float*)d_in[0];
    const float* v      = (const float*)d_in[1];
    float* out          = (float*)d_out;
    unsigned short* wsv = (unsigned short*)d_ws;   // 8 MB of ws used

    vprep_kernel<<<dim3(NBH * 32), dim3(256), 0, stream>>>(v, wsv);
    softmaxv_kernel<<<dim3(256), dim3(512), 0, stream>>>(scores, wsv, out);
}